// Round 1
// baseline (1919.338 us; speedup 1.0000x reference)
//
#include <hip/hip_runtime.h>

// GINEConv + MLP:  out = relu( relu( ((1+eps)*x + scatter_sum(relu(x[src]+ea), dst)) @ W1 + b1 ) @ W2 + b2 )
// N=50000, E=800000, D=128, H=64, DO=256. All fp32 (edge_index -> int32 per harness).

#define D_IN   128
#define H_DIM  64
#define DO_DIM 256

// ---------------- edge stage: msg = relu(x[src]+ea); atomic scatter-add to agg[dst] ----------------
// 32 lanes per edge, float4 per lane (32*4 = 128 features).
__global__ __launch_bounds__(256) void edge_scatter_kernel(
    const float* __restrict__ x,
    const int*   __restrict__ ei,    // [2][E]
    const float* __restrict__ ea,    // [E][128]
    float*       __restrict__ agg,   // [N][128], pre-zeroed
    int E)
{
    int g    = blockIdx.x * blockDim.x + threadIdx.x;
    int edge = g >> 5;
    int lane = g & 31;
    if (edge >= E) return;

    int src = ei[edge];
    int dst = ei[E + edge];

    const float4 a  = *reinterpret_cast<const float4*>(ea + (size_t)edge * D_IN + lane * 4);
    const float4 xv = *reinterpret_cast<const float4*>(x  + (size_t)src  * D_IN + lane * 4);

    float4 m;
    m.x = fmaxf(xv.x + a.x, 0.0f);
    m.y = fmaxf(xv.y + a.y, 0.0f);
    m.z = fmaxf(xv.z + a.z, 0.0f);
    m.w = fmaxf(xv.w + a.w, 0.0f);

    float* p = agg + (size_t)dst * D_IN + lane * 4;
    atomicAdd(p + 0, m.x);
    atomicAdd(p + 1, m.y);
    atomicAdd(p + 2, m.z);
    atomicAdd(p + 3, m.w);
}

// ---------------- node stage: fused (1+eps)*x + agg -> Linear(128->64) -> ReLU -> Linear(64->256) -> ReLU ----------------
// 512 threads = 8 waves / block; one node per wave per pass. Weights staged in LDS (~103 KB -> 1 block/CU).
// LDS access patterns chosen conflict-free: W1[d][j] & W2[j][k] lane-consecutive; h[d], hid[j] broadcast.
__global__ __launch_bounds__(512, 1) void mlp_kernel(
    const float* __restrict__ x,
    const float* __restrict__ agg,
    const float* __restrict__ epsp,
    const float* __restrict__ W1,   // [128][64]
    const float* __restrict__ b1,   // [64]
    const float* __restrict__ W2,   // [64][256]
    const float* __restrict__ b2,   // [256]
    float*       __restrict__ out,  // [N][256]
    int N)
{
    __shared__ float sW1[D_IN * H_DIM];      // 32 KB
    __shared__ float sW2[H_DIM * DO_DIM];    // 64 KB
    __shared__ float sb1[H_DIM];
    __shared__ float sb2[DO_DIM];
    __shared__ float sh[8][D_IN];            // 4 KB, per-wave h
    __shared__ float shid[8][H_DIM];         // 2 KB, per-wave hidden

    const int tid = threadIdx.x;
    for (int i = tid; i < D_IN * H_DIM; i += 512)   sW1[i] = W1[i];
    for (int i = tid; i < H_DIM * DO_DIM; i += 512) sW2[i] = W2[i];
    if (tid < H_DIM)  sb1[tid] = b1[tid];
    if (tid < DO_DIM) sb2[tid] = b2[tid];
    const float eps1 = 1.0f + epsp[0];
    __syncthreads();

    const int wave = tid >> 6;
    const int lane = tid & 63;

    for (int n0 = blockIdx.x * 8; n0 < N; n0 += gridDim.x * 8) {
        const int n = n0 + wave;
        if (n < N) {
            // stage h = (1+eps)*x + agg  (64 lanes x float2 = 128)
            float2 xv = *reinterpret_cast<const float2*>(x   + (size_t)n * D_IN + lane * 2);
            float2 av = *reinterpret_cast<const float2*>(agg + (size_t)n * D_IN + lane * 2);
            sh[wave][lane * 2 + 0] = fmaf(eps1, xv.x, av.x);
            sh[wave][lane * 2 + 1] = fmaf(eps1, xv.y, av.y);
        }
        __syncthreads();
        if (n < N) {
            // hidden[j=lane] = relu( sum_d h[d] * W1[d][j] + b1[j] )
            float acc = sb1[lane];
            #pragma unroll 8
            for (int d = 0; d < D_IN; ++d)
                acc = fmaf(sh[wave][d], sW1[d * H_DIM + lane], acc);
            shid[wave][lane] = fmaxf(acc, 0.0f);
        }
        __syncthreads();
        if (n < N) {
            // out[k] = relu( sum_j hid[j] * W2[j][k] + b2[k] ),  k = lane + {0,64,128,192}
            float o0 = sb2[lane];
            float o1 = sb2[64  + lane];
            float o2 = sb2[128 + lane];
            float o3 = sb2[192 + lane];
            #pragma unroll 8
            for (int j = 0; j < H_DIM; ++j) {
                float hv = shid[wave][j];
                o0 = fmaf(hv, sW2[j * DO_DIM +       lane], o0);
                o1 = fmaf(hv, sW2[j * DO_DIM + 64  + lane], o1);
                o2 = fmaf(hv, sW2[j * DO_DIM + 128 + lane], o2);
                o3 = fmaf(hv, sW2[j * DO_DIM + 192 + lane], o3);
            }
            float* op = out + (size_t)n * DO_DIM;
            op[lane]       = fmaxf(o0, 0.0f);
            op[64  + lane] = fmaxf(o1, 0.0f);
            op[128 + lane] = fmaxf(o2, 0.0f);
            op[192 + lane] = fmaxf(o3, 0.0f);
        }
        __syncthreads();
    }
}

extern "C" void kernel_launch(void* const* d_in, const int* in_sizes, int n_in,
                              void* d_out, int out_size, void* d_ws, size_t ws_size,
                              hipStream_t stream)
{
    const float* x   = (const float*)d_in[0];
    const int*   ei  = (const int*)  d_in[1];
    const float* ea  = (const float*)d_in[2];
    const float* eps = (const float*)d_in[3];
    const float* W1  = (const float*)d_in[4];
    const float* b1  = (const float*)d_in[5];
    const float* W2  = (const float*)d_in[6];
    const float* b2  = (const float*)d_in[7];
    float* out = (float*)d_out;

    const int N = in_sizes[0] / D_IN;
    const int E = in_sizes[1] / 2;

    float* agg = (float*)d_ws;   // [N][128] accumulator
    hipMemsetAsync(agg, 0, (size_t)N * D_IN * sizeof(float), stream);

    {   // edge stage: 8 edges per 256-thread block
        int blocks = (E + 7) / 8;
        edge_scatter_kernel<<<blocks, 256, 0, stream>>>(x, ei, ea, agg, E);
    }
    {   // node stage
        int blocks = 1024;
        mlp_kernel<<<blocks, 512, 0, stream>>>(x, agg, eps, W1, b1, W2, b2, out, N);
    }
}

// Round 2
// 914.137 us; speedup vs baseline: 2.0996x; 2.0996x over previous
//
#include <hip/hip_runtime.h>

// GINEConv + MLP, atomic-free:
//   1) histogram dst, 2) exclusive scan -> CSR offsets, 3) scatter edges sorted by dst,
//   4) gather-aggregate per node: h = (1+eps)*x + sum relu(x[src]+ea), 5) register-tiled fused MLP.
// N=50000, E=800000, D=128, H=64, DO=256, fp32.

#define D_IN   128
#define H_DIM  64
#define DO_DIM 256

// ---------------- 1. histogram of dst ----------------
__global__ __launch_bounds__(256) void hist_kernel(
    const int* __restrict__ ei, int* __restrict__ counts, int E)
{
    int g = blockIdx.x * blockDim.x + threadIdx.x;
    if (g < E) atomicAdd(&counts[ei[E + g]], 1);
}

// ---------------- 2. exclusive scan (single block, 1024 threads) ----------------
__global__ __launch_bounds__(1024) void scan_kernel(
    int* __restrict__ counts,   // in: per-node counts (will be rewritten as running cursor)
    int* __restrict__ offsets,  // out: [N+1] exclusive prefix
    int N)
{
    __shared__ int part[1024];
    const int tid = threadIdx.x;
    const int CH  = (N + 1023) / 1024;
    const int lo  = tid * CH;
    const int hi  = min(lo + CH, N);

    int s = 0;
    for (int i = lo; i < hi; ++i) s += counts[i];
    part[tid] = s;
    __syncthreads();
    // Hillis-Steele inclusive scan
    for (int off = 1; off < 1024; off <<= 1) {
        int v = (tid >= off) ? part[tid - off] : 0;
        __syncthreads();
        part[tid] += v;
        __syncthreads();
    }
    int run = part[tid] - s;   // exclusive base for this chunk
    for (int i = lo; i < hi; ++i) {
        int c = counts[i];
        offsets[i] = run;
        counts[i]  = run;      // becomes the scatter cursor
        run += c;
    }
    if (tid == 1023) offsets[N] = part[1023];
}

// ---------------- 3. scatter edges into dst-sorted order ----------------
__global__ __launch_bounds__(256) void scatter_kernel(
    const int* __restrict__ ei, int* __restrict__ cursor,
    int2* __restrict__ sorted, int E)
{
    int g = blockIdx.x * blockDim.x + threadIdx.x;
    if (g >= E) return;
    int s = ei[g];
    int d = ei[E + g];
    int pos = atomicAdd(&cursor[d], 1);
    sorted[pos] = make_int2(s, g);
}

// ---------------- 4. gather-aggregate: one wave per node ----------------
__global__ __launch_bounds__(512) void agg_kernel(
    const float* __restrict__ x,
    const float* __restrict__ ea,
    const int*  __restrict__ offsets,
    const int2* __restrict__ sorted,
    const float* __restrict__ epsp,
    float* __restrict__ h,     // [N][128] out
    int N)
{
    const int gid  = blockIdx.x * blockDim.x + threadIdx.x;
    const int node = gid >> 6;
    const int lane = gid & 63;
    if (node >= N) return;

    const int beg = offsets[node];
    const int end = offsets[node + 1];

    float2 acc = {0.0f, 0.0f};
    for (int e = beg; e < end; ++e) {
        int2 se = sorted[e];
        const float2 xv = *reinterpret_cast<const float2*>(x  + (size_t)se.x * D_IN + lane * 2);
        const float2 av = *reinterpret_cast<const float2*>(ea + (size_t)se.y * D_IN + lane * 2);
        acc.x += fmaxf(xv.x + av.x, 0.0f);
        acc.y += fmaxf(xv.y + av.y, 0.0f);
    }
    const float eps1 = 1.0f + epsp[0];
    const float2 xn = *reinterpret_cast<const float2*>(x + (size_t)node * D_IN + lane * 2);
    float2 hv;
    hv.x = fmaf(eps1, xn.x, acc.x);
    hv.y = fmaf(eps1, xn.y, acc.y);
    *reinterpret_cast<float2*>(h + (size_t)node * D_IN + lane * 2) = hv;
}

// ---------------- 5. fused MLP, register-tiled ----------------
// 256 threads, 64 nodes/block. tx=tid&15, ty=tid>>4.
// L1: thread computes 4 nodes x 4 hid (hid c = tx*4..tx*4+3), W1 read as float4.
// L2: thread computes 4 nodes x 16 out (out c = 64*jj + tx*4, jj=0..3), W2 read as float4.
#define SH_LD  132   // 128 + 4 pad (bank-conflict-free)
#define SHID_LD 68   // 64 + 4 pad

__global__ __launch_bounds__(256, 1) void mlp_kernel(
    const float* __restrict__ h,
    const float* __restrict__ W1,   // [128][64]
    const float* __restrict__ b1,   // [64]
    const float* __restrict__ W2,   // [64][256]
    const float* __restrict__ b2,   // [256]
    float* __restrict__ out,        // [N][256]
    int N)
{
    __shared__ float sW1[D_IN * H_DIM];        // 32 KB
    __shared__ float sW2[H_DIM * DO_DIM];      // 64 KB
    __shared__ float sh[64 * SH_LD];           // 33 KB
    __shared__ float shid[64 * SHID_LD];       // 17 KB
    __shared__ float sb1[H_DIM];
    __shared__ float sb2[DO_DIM];

    const int tid = threadIdx.x;

    for (int i = tid; i < (D_IN * H_DIM) / 4; i += 256)
        reinterpret_cast<float4*>(sW1)[i] = reinterpret_cast<const float4*>(W1)[i];
    for (int i = tid; i < (H_DIM * DO_DIM) / 4; i += 256)
        reinterpret_cast<float4*>(sW2)[i] = reinterpret_cast<const float4*>(W2)[i];
    if (tid < H_DIM) sb1[tid] = b1[tid];
    sb2[tid] = b2[tid];

    const int n0 = blockIdx.x * 64;

    // stage h tile [64][128] -> sh (padded), float4 loads
    for (int idx = tid; idx < 64 * 32; idx += 256) {
        int n = idx >> 5;
        int f = (idx & 31) * 4;
        int gn = n0 + n;
        float4 v = (gn < N) ? *reinterpret_cast<const float4*>(h + (size_t)gn * D_IN + f)
                            : make_float4(0.f, 0.f, 0.f, 0.f);
        *reinterpret_cast<float4*>(&sh[n * SH_LD + f]) = v;
    }
    __syncthreads();

    const int tx = tid & 15;
    const int ty = tid >> 4;

    // ---- layer 1: hid[n][c] = relu(sum_k h[n][k] * W1[k][c] + b1[c]) ----
    {
        float acc[4][4];
        #pragma unroll
        for (int i = 0; i < 4; ++i)
            #pragma unroll
            for (int j = 0; j < 4; ++j)
                acc[i][j] = sb1[tx * 4 + j];

        #pragma unroll 4
        for (int k = 0; k < D_IN; ++k) {
            float4 w = *reinterpret_cast<const float4*>(&sW1[k * H_DIM + tx * 4]);
            #pragma unroll
            for (int i = 0; i < 4; ++i) {
                float hv = sh[(ty * 4 + i) * SH_LD + k];
                acc[i][0] = fmaf(hv, w.x, acc[i][0]);
                acc[i][1] = fmaf(hv, w.y, acc[i][1]);
                acc[i][2] = fmaf(hv, w.z, acc[i][2]);
                acc[i][3] = fmaf(hv, w.w, acc[i][3]);
            }
        }
        #pragma unroll
        for (int i = 0; i < 4; ++i) {
            float4 r;
            r.x = fmaxf(acc[i][0], 0.f);
            r.y = fmaxf(acc[i][1], 0.f);
            r.z = fmaxf(acc[i][2], 0.f);
            r.w = fmaxf(acc[i][3], 0.f);
            *reinterpret_cast<float4*>(&shid[(ty * 4 + i) * SHID_LD + tx * 4]) = r;
        }
    }
    __syncthreads();

    // ---- layer 2: out[n][c] = relu(sum_k hid[n][k] * W2[k][c] + b2[c]) ----
    {
        float4 o[4][4];
        #pragma unroll
        for (int i = 0; i < 4; ++i)
            #pragma unroll
            for (int jj = 0; jj < 4; ++jj)
                o[i][jj] = *reinterpret_cast<const float4*>(&sb2[jj * 64 + tx * 4]);

        #pragma unroll 4
        for (int k = 0; k < H_DIM; ++k) {
            float4 w[4];
            #pragma unroll
            for (int jj = 0; jj < 4; ++jj)
                w[jj] = *reinterpret_cast<const float4*>(&sW2[k * DO_DIM + jj * 64 + tx * 4]);
            #pragma unroll
            for (int i = 0; i < 4; ++i) {
                float hv = shid[(ty * 4 + i) * SHID_LD + k];
                #pragma unroll
                for (int jj = 0; jj < 4; ++jj) {
                    o[i][jj].x = fmaf(hv, w[jj].x, o[i][jj].x);
                    o[i][jj].y = fmaf(hv, w[jj].y, o[i][jj].y);
                    o[i][jj].z = fmaf(hv, w[jj].z, o[i][jj].z);
                    o[i][jj].w = fmaf(hv, w[jj].w, o[i][jj].w);
                }
            }
        }
        #pragma unroll
        for (int i = 0; i < 4; ++i) {
            int gn = n0 + ty * 4 + i;
            if (gn < N) {
                #pragma unroll
                for (int jj = 0; jj < 4; ++jj) {
                    float4 r;
                    r.x = fmaxf(o[i][jj].x, 0.f);
                    r.y = fmaxf(o[i][jj].y, 0.f);
                    r.z = fmaxf(o[i][jj].z, 0.f);
                    r.w = fmaxf(o[i][jj].w, 0.f);
                    *reinterpret_cast<float4*>(&out[(size_t)gn * DO_DIM + jj * 64 + tx * 4]) = r;
                }
            }
        }
    }
}

extern "C" void kernel_launch(void* const* d_in, const int* in_sizes, int n_in,
                              void* d_out, int out_size, void* d_ws, size_t ws_size,
                              hipStream_t stream)
{
    const float* x   = (const float*)d_in[0];
    const int*   ei  = (const int*)  d_in[1];
    const float* ea  = (const float*)d_in[2];
    const float* eps = (const float*)d_in[3];
    const float* W1  = (const float*)d_in[4];
    const float* b1  = (const float*)d_in[5];
    const float* W2  = (const float*)d_in[6];
    const float* b2  = (const float*)d_in[7];
    float* out = (float*)d_out;

    const int N = in_sizes[0] / D_IN;
    const int E = in_sizes[1] / 2;

    // workspace layout
    char* base = (char*)d_ws;
    float* h       = (float*)base;                                  // N*128 f32
    size_t off_h   = (size_t)N * D_IN * sizeof(float);
    int*   offsets = (int*)(base + off_h);                          // N+1 ints
    int*   cursor  = offsets + (N + 1);                             // N ints (counts -> cursor)
    size_t off_s   = off_h + (size_t)(2 * N + 1) * sizeof(int);
    off_s = (off_s + 7) & ~(size_t)7;
    int2*  sorted  = (int2*)(base + off_s);                         // E int2

    hipMemsetAsync(cursor, 0, (size_t)N * sizeof(int), stream);

    hist_kernel<<<(E + 255) / 256, 256, 0, stream>>>(ei, cursor, E);
    scan_kernel<<<1, 1024, 0, stream>>>(cursor, offsets, N);
    scatter_kernel<<<(E + 255) / 256, 256, 0, stream>>>(ei, cursor, sorted, E);

    {   // aggregate: one wave per node
        int blocks = (N * 64 + 511) / 512;
        agg_kernel<<<blocks, 512, 0, stream>>>(x, ea, offsets, sorted, eps, h, N);
    }
    {   // fused MLP: 64 nodes per block
        int blocks = (N + 63) / 64;
        mlp_kernel<<<blocks, 256, 0, stream>>>(h, W1, b1, W2, b2, out, N);
    }
}

// Round 4
// 865.678 us; speedup vs baseline: 2.2171x; 1.0560x over previous
//
#include <hip/hip_runtime.h>

// GINEConv + MLP, atomic-free CSR pipeline:
//   1) histogram dst, 2) single-block scan -> offsets, 3) scatter edges sorted by dst,
//   4) gather-aggregate (software-pipelined, nontemporal ea) -> h,
//   5) register-tiled fused MLP (weights via L1/L2, only activations in LDS).
// N=50000, E=800000, D=128, H=64, DO=256, fp32.

#define D_IN   128
#define H_DIM  64
#define DO_DIM 256

typedef float v2f __attribute__((ext_vector_type(2)));
typedef int   v4i __attribute__((ext_vector_type(4)));

// ---------------- 1. histogram of dst (4 edges/thread, int4 loads) ----------------
__global__ __launch_bounds__(256) void hist_kernel(
    const int* __restrict__ ei, int* __restrict__ counts, int E)
{
    int g = blockIdx.x * blockDim.x + threadIdx.x;
    int base = g * 4;
    if (base + 4 <= E) {
        int4 d = *reinterpret_cast<const int4*>(ei + E + base);
        atomicAdd(&counts[d.x], 1);
        atomicAdd(&counts[d.y], 1);
        atomicAdd(&counts[d.z], 1);
        atomicAdd(&counts[d.w], 1);
    } else {
        for (int i = base; i < E; ++i) atomicAdd(&counts[ei[E + i]], 1);
    }
}

// ---------------- 2. exclusive scan (single block, 1024 threads) ----------------
__global__ __launch_bounds__(1024) void scan_kernel(
    int* __restrict__ counts,   // in: per-node counts; out: running cursor
    int* __restrict__ offsets,  // out: [N+1] exclusive prefix
    int N)
{
    __shared__ int part[1024];
    const int tid = threadIdx.x;
    const int CH  = (N + 1023) / 1024;
    const int lo  = tid * CH;
    const int hi  = min(lo + CH, N);

    int s = 0;
    for (int i = lo; i < hi; ++i) s += counts[i];
    part[tid] = s;
    __syncthreads();
    for (int off = 1; off < 1024; off <<= 1) {
        int v = (tid >= off) ? part[tid - off] : 0;
        __syncthreads();
        part[tid] += v;
        __syncthreads();
    }
    int run = part[tid] - s;
    for (int i = lo; i < hi; ++i) {
        int c = counts[i];
        offsets[i] = run;
        counts[i]  = run;
        run += c;
    }
    if (tid == 1023) offsets[N] = part[1023];
}

// ---------------- 3. scatter edges into dst-sorted order (4 edges/thread) ----------------
__global__ __launch_bounds__(256) void scatter_kernel(
    const int* __restrict__ ei, int* __restrict__ cursor,
    int2* __restrict__ sorted, int E)
{
    int g = blockIdx.x * blockDim.x + threadIdx.x;
    int base = g * 4;
    if (base + 4 <= E) {
        int4 s = *reinterpret_cast<const int4*>(ei + base);
        int4 d = *reinterpret_cast<const int4*>(ei + E + base);
        int p0 = atomicAdd(&cursor[d.x], 1); sorted[p0] = make_int2(s.x, base + 0);
        int p1 = atomicAdd(&cursor[d.y], 1); sorted[p1] = make_int2(s.y, base + 1);
        int p2 = atomicAdd(&cursor[d.z], 1); sorted[p2] = make_int2(s.z, base + 2);
        int p3 = atomicAdd(&cursor[d.w], 1); sorted[p3] = make_int2(s.w, base + 3);
    } else {
        for (int i = base; i < E; ++i) {
            int pos = atomicAdd(&cursor[ei[E + i]], 1);
            sorted[pos] = make_int2(ei[i], i);
        }
    }
}

// ---------------- 4. gather-aggregate: one wave per node, 2 edges/iter pipelined ----------------
__global__ __launch_bounds__(512) void agg_kernel(
    const float* __restrict__ x,
    const float* __restrict__ ea,
    const int*  __restrict__ offsets,
    const int*  __restrict__ sorted_raw,   // int pairs (src, eid)
    const float* __restrict__ epsp,
    float* __restrict__ h,                 // [N][128] out
    int N)
{
    const int gid  = blockIdx.x * blockDim.x + threadIdx.x;
    const int node = gid >> 6;
    const int lane = gid & 63;
    if (node >= N) return;

    int beg       = offsets[node];
    const int end = offsets[node + 1];

    const float* xb = x  + lane * 2;
    const float* eb = ea + lane * 2;

    v2f acc = {0.0f, 0.0f};

    // peel to even index so int4 pair-loads are 16B aligned
    if ((beg & 1) && beg < end) {
        int src = sorted_raw[beg * 2];
        int eid = sorted_raw[beg * 2 + 1];
        v2f xv = *reinterpret_cast<const v2f*>(xb + (size_t)src * D_IN);
        v2f av = __builtin_nontemporal_load(reinterpret_cast<const v2f*>(eb + (size_t)eid * D_IN));
        acc.x += fmaxf(xv.x + av.x, 0.0f);
        acc.y += fmaxf(xv.y + av.y, 0.0f);
        ++beg;
    }

    int e = beg;
    if (e + 2 <= end) {
        v4i cur = __builtin_nontemporal_load(reinterpret_cast<const v4i*>(sorted_raw + e * 2));
        for (;;) {
            const int en = e + 2;
            const bool more = (en + 2 <= end);
            v4i nxt;
            if (more) nxt = __builtin_nontemporal_load(reinterpret_cast<const v4i*>(sorted_raw + en * 2));
            // 4 independent row loads (x cached, ea streamed nontemporal)
            v2f x0 = *reinterpret_cast<const v2f*>(xb + (size_t)cur.x * D_IN);
            v2f a0 = __builtin_nontemporal_load(reinterpret_cast<const v2f*>(eb + (size_t)cur.y * D_IN));
            v2f x1 = *reinterpret_cast<const v2f*>(xb + (size_t)cur.z * D_IN);
            v2f a1 = __builtin_nontemporal_load(reinterpret_cast<const v2f*>(eb + (size_t)cur.w * D_IN));
            acc.x += fmaxf(x0.x + a0.x, 0.0f) + fmaxf(x1.x + a1.x, 0.0f);
            acc.y += fmaxf(x0.y + a0.y, 0.0f) + fmaxf(x1.y + a1.y, 0.0f);
            e = en;
            if (!more) break;
            cur = nxt;
        }
    }
    if (e < end) {   // tail (0 or 1 edge)
        int src = sorted_raw[e * 2];
        int eid = sorted_raw[e * 2 + 1];
        v2f xv = *reinterpret_cast<const v2f*>(xb + (size_t)src * D_IN);
        v2f av = __builtin_nontemporal_load(reinterpret_cast<const v2f*>(eb + (size_t)eid * D_IN));
        acc.x += fmaxf(xv.x + av.x, 0.0f);
        acc.y += fmaxf(xv.y + av.y, 0.0f);
    }

    const float eps1 = 1.0f + epsp[0];
    v2f xn = *reinterpret_cast<const v2f*>(xb + (size_t)node * D_IN);
    v2f hv;
    hv.x = fmaf(eps1, xn.x, acc.x);
    hv.y = fmaf(eps1, xn.y, acc.y);
    *reinterpret_cast<v2f*>(h + (size_t)node * D_IN + lane * 2) = hv;
}

// ---------------- 5. fused MLP, register-tiled; weights via L1/L2, activations in LDS ----------------
// 256 threads, 64 nodes/block. tx=tid&15 (feature tile), ty=tid>>4 (node tile).
// LDS = sh(33.8KB) + shid(17.4KB) ~= 51KB -> 3 blocks/CU (12 waves/CU).
#define SH_LD   132   // 128 + 4 pad
#define SHID_LD 68    // 64 + 4 pad

__global__ __launch_bounds__(256, 3) void mlp_kernel(
    const float* __restrict__ h,
    const float* __restrict__ W1,   // [128][64]
    const float* __restrict__ b1,   // [64]
    const float* __restrict__ W2,   // [64][256]
    const float* __restrict__ b2,   // [256]
    float* __restrict__ out,        // [N][256]
    int N)
{
    __shared__ float sh[64 * SH_LD];
    __shared__ float shid[64 * SHID_LD];

    const int tid = threadIdx.x;
    const int n0 = blockIdx.x * 64;

    // stage h tile [64][128] -> sh (padded), float4 loads
    for (int idx = tid; idx < 64 * 32; idx += 256) {
        int n = idx >> 5;
        int f = (idx & 31) * 4;
        int gn = n0 + n;
        float4 v = (gn < N) ? *reinterpret_cast<const float4*>(h + (size_t)gn * D_IN + f)
                            : make_float4(0.f, 0.f, 0.f, 0.f);
        *reinterpret_cast<float4*>(&sh[n * SH_LD + f]) = v;
    }
    __syncthreads();

    const int tx = tid & 15;
    const int ty = tid >> 4;

    // ---- layer 1: hid[n][c] = relu(sum_k h[n][k] * W1[k][c] + b1[c]) ----
    {
        float4 bv = *reinterpret_cast<const float4*>(b1 + tx * 4);
        float acc[4][4];
        #pragma unroll
        for (int i = 0; i < 4; ++i) {
            acc[i][0] = bv.x; acc[i][1] = bv.y; acc[i][2] = bv.z; acc[i][3] = bv.w;
        }
        #pragma unroll 4
        for (int k = 0; k < D_IN; ++k) {
            float4 w = *reinterpret_cast<const float4*>(W1 + k * H_DIM + tx * 4);
            #pragma unroll
            for (int i = 0; i < 4; ++i) {
                float hv = sh[(ty * 4 + i) * SH_LD + k];
                acc[i][0] = fmaf(hv, w.x, acc[i][0]);
                acc[i][1] = fmaf(hv, w.y, acc[i][1]);
                acc[i][2] = fmaf(hv, w.z, acc[i][2]);
                acc[i][3] = fmaf(hv, w.w, acc[i][3]);
            }
        }
        #pragma unroll
        for (int i = 0; i < 4; ++i) {
            float4 r;
            r.x = fmaxf(acc[i][0], 0.f);
            r.y = fmaxf(acc[i][1], 0.f);
            r.z = fmaxf(acc[i][2], 0.f);
            r.w = fmaxf(acc[i][3], 0.f);
            *reinterpret_cast<float4*>(&shid[(ty * 4 + i) * SHID_LD + tx * 4]) = r;
        }
    }
    __syncthreads();

    // ---- layer 2: out[n][c] = relu(sum_k hid[n][k] * W2[k][c] + b2[c]) ----
    {
        float4 o[4][4];
        #pragma unroll
        for (int jj = 0; jj < 4; ++jj) {
            float4 bv = *reinterpret_cast<const float4*>(b2 + jj * 64 + tx * 4);
            #pragma unroll
            for (int i = 0; i < 4; ++i) o[i][jj] = bv;
        }
        #pragma unroll 2
        for (int k = 0; k < H_DIM; ++k) {
            float4 w[4];
            #pragma unroll
            for (int jj = 0; jj < 4; ++jj)
                w[jj] = *reinterpret_cast<const float4*>(W2 + k * DO_DIM + jj * 64 + tx * 4);
            #pragma unroll
            for (int i = 0; i < 4; ++i) {
                float hv = shid[(ty * 4 + i) * SHID_LD + k];
                #pragma unroll
                for (int jj = 0; jj < 4; ++jj) {
                    o[i][jj].x = fmaf(hv, w[jj].x, o[i][jj].x);
                    o[i][jj].y = fmaf(hv, w[jj].y, o[i][jj].y);
                    o[i][jj].z = fmaf(hv, w[jj].z, o[i][jj].z);
                    o[i][jj].w = fmaf(hv, w[jj].w, o[i][jj].w);
                }
            }
        }
        #pragma unroll
        for (int i = 0; i < 4; ++i) {
            int gn = n0 + ty * 4 + i;
            if (gn < N) {
                #pragma unroll
                for (int jj = 0; jj < 4; ++jj) {
                    float4 r;
                    r.x = fmaxf(o[i][jj].x, 0.f);
                    r.y = fmaxf(o[i][jj].y, 0.f);
                    r.z = fmaxf(o[i][jj].z, 0.f);
                    r.w = fmaxf(o[i][jj].w, 0.f);
                    *reinterpret_cast<float4*>(&out[(size_t)gn * DO_DIM + jj * 64 + tx * 4]) = r;
                }
            }
        }
    }
}

extern "C" void kernel_launch(void* const* d_in, const int* in_sizes, int n_in,
                              void* d_out, int out_size, void* d_ws, size_t ws_size,
                              hipStream_t stream)
{
    const float* x   = (const float*)d_in[0];
    const int*   ei  = (const int*)  d_in[1];
    const float* ea  = (const float*)d_in[2];
    const float* eps = (const float*)d_in[3];
    const float* W1  = (const float*)d_in[4];
    const float* b1  = (const float*)d_in[5];
    const float* W2  = (const float*)d_in[6];
    const float* b2  = (const float*)d_in[7];
    float* out = (float*)d_out;

    const int N = in_sizes[0] / D_IN;
    const int E = in_sizes[1] / 2;

    // workspace layout (16B-aligned sorted)
    char* base = (char*)d_ws;
    float* h       = (float*)base;                                  // N*128 f32
    size_t off_h   = (size_t)N * D_IN * sizeof(float);
    int*   offsets = (int*)(base + off_h);                          // N+1 ints
    int*   cursor  = offsets + (N + 1);                             // N ints
    size_t off_s   = off_h + (size_t)(2 * N + 1) * sizeof(int);
    off_s = (off_s + 15) & ~(size_t)15;
    int2*  sorted  = (int2*)(base + off_s);                         // E int2

    hipMemsetAsync(cursor, 0, (size_t)N * sizeof(int), stream);

    hist_kernel<<<(E / 4 + 255) / 256, 256, 0, stream>>>(ei, cursor, E);
    scan_kernel<<<1, 1024, 0, stream>>>(cursor, offsets, N);
    scatter_kernel<<<(E / 4 + 255) / 256, 256, 0, stream>>>(ei, cursor, sorted, E);

    {   // aggregate: one wave per node
        int blocks = (N * 64 + 511) / 512;
        agg_kernel<<<blocks, 512, 0, stream>>>(x, ea, offsets, (const int*)sorted, eps, h, N);
    }
    {   // fused MLP: 64 nodes per block
        int blocks = (N + 63) / 64;
        mlp_kernel<<<blocks, 256, 0, stream>>>(h, W1, b1, W2, b2, out, N);
    }
}